// Round 1
// baseline (5716.882 us; speedup 1.0000x reference)
//
#include <hip/hip_runtime.h>

static constexpr int D1 = 128;   // ninp
// layer widths: 128 -> 256 -> 128

// ---------------- degree / norm ----------------
__global__ void k_init_deg(float* __restrict__ deg, int n) {
  int i = blockIdx.x * blockDim.x + threadIdx.x;
  if (i < n) deg[i] = 1.0f;  // self-loop
}

__global__ void k_count(const int* __restrict__ dst, float* __restrict__ deg, int e) {
  int i = blockIdx.x * blockDim.x + threadIdx.x;
  if (i < e) atomicAdd(&deg[dst[i]], 1.0f);
}

__global__ void k_rsqrt(float* __restrict__ deg, int n) {
  int i = blockIdx.x * blockDim.x + threadIdx.x;
  if (i < n) deg[i] = rsqrtf(deg[i]);  // deg >= 1 always
}

// ---------------- aggregation (width 128) ----------------
// y[i][:] = (bias ? bias : 0) + x[i][:] * dinv[i]^2      (self-loop term + optional bias)
__global__ void k_self(const float* __restrict__ x, const float* __restrict__ dinv,
                       const float* __restrict__ bias, float* __restrict__ y, int n) {
  int t = blockIdx.x * blockDim.x + threadIdx.x;
  int i = t >> 5, c4 = t & 31;           // 32 float4 lanes per row
  if (i >= n) return;
  float di = dinv[i];
  float s = di * di;
  float4 v = ((const float4*)(x + (size_t)i * D1))[c4];
  float4 o;
  if (bias) {
    float4 b = ((const float4*)bias)[c4];
    o.x = fmaf(v.x, s, b.x); o.y = fmaf(v.y, s, b.y);
    o.z = fmaf(v.z, s, b.z); o.w = fmaf(v.w, s, b.w);
  } else {
    o.x = v.x * s; o.y = v.y * s; o.z = v.z * s; o.w = v.w * s;
  }
  ((float4*)(y + (size_t)i * D1))[c4] = o;
}

// y[dst][:] += x[src][:] * dinv[src] * dinv[dst], one half-wave (32 lanes) per edge
__global__ void k_edge(const int* __restrict__ src, const int* __restrict__ dst,
                       const float* __restrict__ dinv, const float* __restrict__ x,
                       float* __restrict__ y, int e) {
  int t = blockIdx.x * blockDim.x + threadIdx.x;
  int ei = t >> 5, c4 = t & 31;
  if (ei >= e) return;
  int s = src[ei], d = dst[ei];
  float nrm = dinv[s] * dinv[d];
  float4 v = ((const float4*)(x + (size_t)s * D1))[c4];
  float* yp = y + (size_t)d * D1 + c4 * 4;
  atomicAdd(yp + 0, v.x * nrm);
  atomicAdd(yp + 1, v.y * nrm);
  atomicAdd(yp + 2, v.z * nrm);
  atomicAdd(yp + 3, v.w * nrm);
}

// ---------------- fp32 GEMM: Y[n,NC] = X[n,K] @ W[K,NC] (+bias) ----------------
// 64x64 block tile, 16x16 threads, 4x4 per thread; X tile staged in LDS (pad 133 -> <=2-way conflicts)
template<int K, int NC, bool BIAS>
__global__ __launch_bounds__(256) void k_gemm(const float* __restrict__ X,
                                              const float* __restrict__ W,
                                              const float* __restrict__ bias,
                                              float* __restrict__ Y, int n) {
  __shared__ float xs[64][133];
  const int tx = threadIdx.x & 15;
  const int ty = threadIdx.x >> 4;
  const int ty4 = ty * 4;
  const int row0 = blockIdx.x * 64;
  const int col0 = blockIdx.y * 64 + tx * 4;

  float acc[4][4] = {};

  for (int k0 = 0; k0 < K; k0 += 128) {
    __syncthreads();
    // stage 64 rows x 128 k (2048 float4, 8 per thread), coalesced global reads
    #pragma unroll
    for (int i = 0; i < 8; ++i) {
      int flat4 = threadIdx.x + i * 256;
      int r = flat4 >> 5;          // 32 float4 per row
      int kk = (flat4 & 31) * 4;
      float4 v = make_float4(0.f, 0.f, 0.f, 0.f);
      if (row0 + r < n) v = *(const float4*)(X + (size_t)(row0 + r) * K + k0 + kk);
      xs[r][kk + 0] = v.x; xs[r][kk + 1] = v.y; xs[r][kk + 2] = v.z; xs[r][kk + 3] = v.w;
    }
    __syncthreads();

    #pragma unroll 8
    for (int k = 0; k < 128; ++k) {
      float4 w4 = *(const float4*)(W + (size_t)(k0 + k) * NC + col0);
      float xa = xs[ty4 + 0][k];
      float xb = xs[ty4 + 1][k];
      float xc = xs[ty4 + 2][k];
      float xd = xs[ty4 + 3][k];
      acc[0][0] = fmaf(xa, w4.x, acc[0][0]); acc[0][1] = fmaf(xa, w4.y, acc[0][1]);
      acc[0][2] = fmaf(xa, w4.z, acc[0][2]); acc[0][3] = fmaf(xa, w4.w, acc[0][3]);
      acc[1][0] = fmaf(xb, w4.x, acc[1][0]); acc[1][1] = fmaf(xb, w4.y, acc[1][1]);
      acc[1][2] = fmaf(xb, w4.z, acc[1][2]); acc[1][3] = fmaf(xb, w4.w, acc[1][3]);
      acc[2][0] = fmaf(xc, w4.x, acc[2][0]); acc[2][1] = fmaf(xc, w4.y, acc[2][1]);
      acc[2][2] = fmaf(xc, w4.z, acc[2][2]); acc[2][3] = fmaf(xc, w4.w, acc[2][3]);
      acc[3][0] = fmaf(xd, w4.x, acc[3][0]); acc[3][1] = fmaf(xd, w4.y, acc[3][1]);
      acc[3][2] = fmaf(xd, w4.z, acc[3][2]); acc[3][3] = fmaf(xd, w4.w, acc[3][3]);
    }
  }

  float4 b4 = make_float4(0.f, 0.f, 0.f, 0.f);
  if (BIAS) b4 = *(const float4*)(bias + col0);
  #pragma unroll
  for (int r = 0; r < 4; ++r) {
    int row = row0 + ty4 + r;
    if (row < n) {
      float4 o;
      o.x = acc[r][0] + b4.x; o.y = acc[r][1] + b4.y;
      o.z = acc[r][2] + b4.z; o.w = acc[r][3] + b4.w;
      *(float4*)(Y + (size_t)row * NC + col0) = o;
    }
  }
}

extern "C" void kernel_launch(void* const* d_in, const int* in_sizes, int n_in,
                              void* d_out, int out_size, void* d_ws, size_t ws_size,
                              hipStream_t stream) {
  const float* emb = (const float*)d_in[0];   // [n,128]
  const float* W1  = (const float*)d_in[1];   // [128,256]
  const float* b1  = (const float*)d_in[2];   // [256]
  const float* W2  = (const float*)d_in[3];   // [256,128]
  const float* b2  = (const float*)d_in[4];   // [128]
  const int*   ei  = (const int*)d_in[5];     // [2,E]

  const int n = in_sizes[0] / D1;
  const int e = in_sizes[5] / 2;
  const int* src = ei;
  const int* dst = ei + e;

  char* ws = (char*)d_ws;
  float* dinv = (float*)ws;                              // n floats (deg -> dinv in place)
  float* agg0 = (float*)(ws + 400384);                   // n*128 floats (also reused as h2)
  float* x1   = (float*)(ws + 400384 + (size_t)n * D1 * 4); // n*256 floats
  float* h2   = agg0;
  float* out  = (float*)d_out;

  const int B = 256;
  // 1. degrees -> dinv
  k_init_deg<<<(n + B - 1) / B, B, 0, stream>>>(dinv, n);
  k_count<<<(e + B - 1) / B, B, 0, stream>>>(dst, dinv, e);
  k_rsqrt<<<(n + B - 1) / B, B, 0, stream>>>(dinv, n);

  // 2. agg0 = A * emb   (width 128)
  {
    long long t = (long long)n * 32;
    k_self<<<(int)((t + B - 1) / B), B, 0, stream>>>(emb, dinv, nullptr, agg0, n);
    long long te = (long long)e * 32;
    k_edge<<<(int)((te + B - 1) / B), B, 0, stream>>>(src, dst, dinv, emb, agg0, e);
  }

  // 3. x1 = agg0 @ W1 + b1
  {
    dim3 grid((n + 63) / 64, 256 / 64);
    k_gemm<128, 256, true><<<grid, 256, 0, stream>>>(agg0, W1, b1, x1, n);
  }

  // 4. h2 = x1 @ W2
  {
    dim3 grid((n + 63) / 64, 128 / 64);
    k_gemm<256, 128, false><<<grid, 256, 0, stream>>>(x1, W2, nullptr, h2, n);
  }

  // 5. out = A * h2 + b2   (width 128)
  {
    long long t = (long long)n * 32;
    k_self<<<(int)((t + B - 1) / B), B, 0, stream>>>(h2, dinv, b2, out, n);
    long long te = (long long)e * 32;
    k_edge<<<(int)((te + B - 1) / B), B, 0, stream>>>(src, dst, dinv, h2, out, e);
  }
}

// Round 2
// 903.711 us; speedup vs baseline: 6.3260x; 6.3260x over previous
//
#include <hip/hip_runtime.h>

static constexpr int D = 128;   // feature width everywhere after the W1*W2 fold

// ---------------- small prep kernels ----------------
__global__ void k_zero_i(int* __restrict__ p, int n) {
  int i = blockIdx.x * blockDim.x + threadIdx.x;
  if (i < n) p[i] = 0;
}

__global__ void k_count(const int* __restrict__ dst, int* __restrict__ cnt, int e) {
  int i = blockIdx.x * blockDim.x + threadIdx.x;
  if (i < e) atomicAdd(&cnt[dst[i]], 1);
}

__global__ void k_dinv(const int* __restrict__ cnt, float* __restrict__ dinv, int n) {
  int i = blockIdx.x * blockDim.x + threadIdx.x;
  if (i < n) dinv[i] = rsqrtf(1.0f + (float)cnt[i]);   // +1 self-loop; always > 0
}

// single-block exclusive scan of cnt[0..n) -> rowptr[0..n), rowptr[n]=e; cursor=rowptr
__global__ void k_scan(const int* __restrict__ cnt, int* __restrict__ rowptr,
                       int* __restrict__ cursor, int n, int e) {
  __shared__ int sh[256];
  __shared__ int carry;
  const int tid = threadIdx.x;
  if (tid == 0) carry = 0;
  __syncthreads();
  for (int base = 0; base < n; base += 256) {
    int i = base + tid;
    int v = (i < n) ? cnt[i] : 0;
    sh[tid] = v;
    __syncthreads();
    #pragma unroll
    for (int off = 1; off < 256; off <<= 1) {
      int t = (tid >= off) ? sh[tid - off] : 0;
      __syncthreads();
      sh[tid] += t;
      __syncthreads();
    }
    int incl = sh[tid];
    int excl = carry + incl - v;
    if (i < n) { rowptr[i] = excl; cursor[i] = excl; }
    __syncthreads();                  // everyone has read carry
    if (tid == 255) carry += incl;    // chunk total
    __syncthreads();
  }
  if (tid == 0) rowptr[n] = e;
}

// csr[pos] = {src, dinv[src]*dinv[dst]} bucketed by dst
__global__ void k_scatter(const int* __restrict__ src, const int* __restrict__ dst,
                          const float* __restrict__ dinv, int* __restrict__ cursor,
                          int2* __restrict__ csr, int e) {
  int i = blockIdx.x * blockDim.x + threadIdx.x;
  if (i >= e) return;
  int s = src[i], d = dst[i];
  int pos = atomicAdd(&cursor[d], 1);
  float w = dinv[s] * dinv[d];
  csr[pos] = make_int2(s, __float_as_int(w));
}

// W = W1[128,256] @ W2[256,128]; c2 = b1 @ W2
__global__ void k_w1w2(const float* __restrict__ W1, const float* __restrict__ W2,
                       const float* __restrict__ b1, float* __restrict__ W,
                       float* __restrict__ c2) {
  int r = blockIdx.x, c = threadIdx.x;   // 128 x 128
  float acc = 0.f;
  for (int k = 0; k < 256; ++k) acc = fmaf(W1[r * 256 + k], W2[k * D + c], acc);
  W[r * D + c] = acc;
  if (r == 0) {
    float a2 = 0.f;
    for (int k = 0; k < 256; ++k) a2 = fmaf(b1[k], W2[k * D + c], a2);
    c2[c] = a2;
  }
}

// ---------------- CSR aggregation: y[i] = dinv[i]^2*x[i] + sum_j w_j*x[src_j] (+bias) ----------------
template<bool BIAS>
__global__ __launch_bounds__(256) void k_agg(const float4* __restrict__ x,
                                             const int* __restrict__ rowptr,
                                             const int2* __restrict__ csr,
                                             const float* __restrict__ dinv,
                                             const float* __restrict__ bias,
                                             float4* __restrict__ y, int n) {
  int t = blockIdx.x * blockDim.x + threadIdx.x;
  int node = t >> 5, lane = t & 31;      // 32 float4 lanes per node row
  if (node >= n) return;
  float di = dinv[node];
  float s = di * di;
  float4 v = x[(size_t)node * 32 + lane];
  float4 acc;
  acc.x = v.x * s; acc.y = v.y * s; acc.z = v.z * s; acc.w = v.w * s;
  if (BIAS) {
    float4 b = ((const float4*)bias)[lane];
    acc.x += b.x; acc.y += b.y; acc.z += b.z; acc.w += b.w;
  }
  int j = rowptr[node], end = rowptr[node + 1];
  // 4-wide unroll: 4 independent row gathers in flight
  for (; j + 4 <= end; j += 4) {
    int2 e0 = csr[j], e1 = csr[j + 1], e2 = csr[j + 2], e3 = csr[j + 3];
    float4 v0 = x[(size_t)e0.x * 32 + lane];
    float4 v1 = x[(size_t)e1.x * 32 + lane];
    float4 v2 = x[(size_t)e2.x * 32 + lane];
    float4 v3 = x[(size_t)e3.x * 32 + lane];
    float w0 = __int_as_float(e0.y), w1 = __int_as_float(e1.y);
    float w2 = __int_as_float(e2.y), w3 = __int_as_float(e3.y);
    acc.x = fmaf(v0.x, w0, acc.x); acc.y = fmaf(v0.y, w0, acc.y);
    acc.z = fmaf(v0.z, w0, acc.z); acc.w = fmaf(v0.w, w0, acc.w);
    acc.x = fmaf(v1.x, w1, acc.x); acc.y = fmaf(v1.y, w1, acc.y);
    acc.z = fmaf(v1.z, w1, acc.z); acc.w = fmaf(v1.w, w1, acc.w);
    acc.x = fmaf(v2.x, w2, acc.x); acc.y = fmaf(v2.y, w2, acc.y);
    acc.z = fmaf(v2.z, w2, acc.z); acc.w = fmaf(v2.w, w2, acc.w);
    acc.x = fmaf(v3.x, w3, acc.x); acc.y = fmaf(v3.y, w3, acc.y);
    acc.z = fmaf(v3.z, w3, acc.z); acc.w = fmaf(v3.w, w3, acc.w);
  }
  for (; j < end; ++j) {
    int2 e0 = csr[j];
    float w0 = __int_as_float(e0.y);
    float4 v0 = x[(size_t)e0.x * 32 + lane];
    acc.x = fmaf(v0.x, w0, acc.x); acc.y = fmaf(v0.y, w0, acc.y);
    acc.z = fmaf(v0.z, w0, acc.z); acc.w = fmaf(v0.w, w0, acc.w);
  }
  y[(size_t)node * 32 + lane] = acc;
}

// ---------------- fp32 GEMM: Y[n,NC] = X[n,K] @ W[K,NC] (+bias) ----------------
template<int K, int NC, bool BIAS>
__global__ __launch_bounds__(256) void k_gemm(const float* __restrict__ X,
                                              const float* __restrict__ W,
                                              const float* __restrict__ bias,
                                              float* __restrict__ Y, int n) {
  __shared__ float xs[64][133];
  const int tx = threadIdx.x & 15;
  const int ty = threadIdx.x >> 4;
  const int ty4 = ty * 4;
  const int row0 = blockIdx.x * 64;
  const int col0 = blockIdx.y * 64 + tx * 4;

  float acc[4][4] = {};

  for (int k0 = 0; k0 < K; k0 += 128) {
    __syncthreads();
    #pragma unroll
    for (int i = 0; i < 8; ++i) {
      int flat4 = threadIdx.x + i * 256;
      int r = flat4 >> 5;
      int kk = (flat4 & 31) * 4;
      float4 v = make_float4(0.f, 0.f, 0.f, 0.f);
      if (row0 + r < n) v = *(const float4*)(X + (size_t)(row0 + r) * K + k0 + kk);
      xs[r][kk + 0] = v.x; xs[r][kk + 1] = v.y; xs[r][kk + 2] = v.z; xs[r][kk + 3] = v.w;
    }
    __syncthreads();

    #pragma unroll 8
    for (int k = 0; k < 128; ++k) {
      float4 w4 = *(const float4*)(W + (size_t)(k0 + k) * NC + col0);
      float xa = xs[ty4 + 0][k];
      float xb = xs[ty4 + 1][k];
      float xc = xs[ty4 + 2][k];
      float xd = xs[ty4 + 3][k];
      acc[0][0] = fmaf(xa, w4.x, acc[0][0]); acc[0][1] = fmaf(xa, w4.y, acc[0][1]);
      acc[0][2] = fmaf(xa, w4.z, acc[0][2]); acc[0][3] = fmaf(xa, w4.w, acc[0][3]);
      acc[1][0] = fmaf(xb, w4.x, acc[1][0]); acc[1][1] = fmaf(xb, w4.y, acc[1][1]);
      acc[1][2] = fmaf(xb, w4.z, acc[1][2]); acc[1][3] = fmaf(xb, w4.w, acc[1][3]);
      acc[2][0] = fmaf(xc, w4.x, acc[2][0]); acc[2][1] = fmaf(xc, w4.y, acc[2][1]);
      acc[2][2] = fmaf(xc, w4.z, acc[2][2]); acc[2][3] = fmaf(xc, w4.w, acc[2][3]);
      acc[3][0] = fmaf(xd, w4.x, acc[3][0]); acc[3][1] = fmaf(xd, w4.y, acc[3][1]);
      acc[3][2] = fmaf(xd, w4.z, acc[3][2]); acc[3][3] = fmaf(xd, w4.w, acc[3][3]);
    }
  }

  float4 b4 = make_float4(0.f, 0.f, 0.f, 0.f);
  if (BIAS) b4 = *(const float4*)(bias + col0);
  #pragma unroll
  for (int r = 0; r < 4; ++r) {
    int row = row0 + ty4 + r;
    if (row < n) {
      float4 o;
      o.x = acc[r][0] + b4.x; o.y = acc[r][1] + b4.y;
      o.z = acc[r][2] + b4.z; o.w = acc[r][3] + b4.w;
      *(float4*)(Y + (size_t)row * NC + col0) = o;
    }
  }
}

extern "C" void kernel_launch(void* const* d_in, const int* in_sizes, int n_in,
                              void* d_out, int out_size, void* d_ws, size_t ws_size,
                              hipStream_t stream) {
  const float* emb = (const float*)d_in[0];   // [n,128]
  const float* W1  = (const float*)d_in[1];   // [128,256]
  const float* b1  = (const float*)d_in[2];   // [256]
  const float* W2  = (const float*)d_in[3];   // [256,128]
  const float* b2  = (const float*)d_in[4];   // [128]
  const int*   ei  = (const int*)d_in[5];     // [2,E] (int32 by harness)

  const int n = in_sizes[0] / D;
  const int e = in_sizes[5] / 2;
  const int* src = ei;
  const int* dst = ei + e;

  // workspace carve-up (all 256B-aligned)
  char* ws = (char*)d_ws;
  size_t off = 0;
  auto alloc = [&](size_t bytes) { void* p = ws + off; off = (off + bytes + 255) & ~(size_t)255; return p; };
  int*   cnt    = (int*)  alloc((size_t)n * 4);
  float* dinv   = (float*)alloc((size_t)n * 4);
  int*   rowptr = (int*)  alloc((size_t)(n + 1) * 4);
  int*   cursor = (int*)  alloc((size_t)n * 4);
  int2*  csr    = (int2*) alloc((size_t)e * 8);
  float* Wc     = (float*)alloc((size_t)D * D * 4);
  float* c2     = (float*)alloc((size_t)D * 4);
  float* S1     = (float*)alloc((size_t)n * D * 4);
  float* Z      = (float*)alloc((size_t)n * D * 4);
  float* out    = (float*)d_out;

  const int B = 256;
  const int gn = (n + B - 1) / B;
  const int ge = (e + B - 1) / B;

  // CSR build + norms
  k_zero_i<<<gn, B, 0, stream>>>(cnt, n);
  k_count<<<ge, B, 0, stream>>>(dst, cnt, e);
  k_dinv<<<gn, B, 0, stream>>>(cnt, dinv, n);
  k_scan<<<1, B, 0, stream>>>(cnt, rowptr, cursor, n, e);
  k_scatter<<<ge, B, 0, stream>>>(src, dst, dinv, cursor, csr, e);

  // fold W = W1@W2, c2 = b1@W2
  k_w1w2<<<D, D, 0, stream>>>(W1, W2, b1, Wc, c2);

  // S1 = A * emb
  {
    long long t = (long long)n * 32;
    k_agg<false><<<(int)((t + B - 1) / B), B, 0, stream>>>(
        (const float4*)emb, rowptr, csr, dinv, nullptr, (float4*)S1, n);
  }
  // Z = S1 @ W + c2
  {
    dim3 grid((n + 63) / 64, D / 64);
    k_gemm<128, 128, true><<<grid, 256, 0, stream>>>(S1, Wc, c2, Z, n);
  }
  // out = A * Z + b2
  {
    long long t = (long long)n * 32;
    k_agg<true><<<(int)((t + B - 1) / B), B, 0, stream>>>(
        (const float4*)Z, rowptr, csr, dinv, b2, (float4*)out, n);
  }
}

// Round 3
// 494.925 us; speedup vs baseline: 11.5510x; 1.8260x over previous
//
#include <hip/hip_runtime.h>

static constexpr int D = 128;   // feature width everywhere after the W1*W2 fold

// ---------------- small prep kernels ----------------
__global__ void k_zero_i(int* __restrict__ p, int n) {
  int i = blockIdx.x * blockDim.x + threadIdx.x;
  if (i < n) p[i] = 0;
}

__global__ void k_count(const int* __restrict__ dst, int* __restrict__ cnt, int e) {
  int i = blockIdx.x * blockDim.x + threadIdx.x;
  if (i < e) atomicAdd(&cnt[dst[i]], 1);
}

__global__ void k_dinv(const int* __restrict__ cnt, float* __restrict__ dinv, int n) {
  int i = blockIdx.x * blockDim.x + threadIdx.x;
  if (i < n) dinv[i] = rsqrtf(1.0f + (float)cnt[i]);   // +1 self-loop; always > 0
}

// ---------------- hierarchical scan (3 kernels) ----------------
// 1) per-block exclusive scan of cnt -> rowptr (local), block total -> bsum[b]
__global__ __launch_bounds__(256) void k_scan1(const int* __restrict__ cnt,
                                               int* __restrict__ rowptr,
                                               int* __restrict__ bsum, int n) {
  __shared__ int sh[256];
  int tid = threadIdx.x;
  int i = blockIdx.x * 256 + tid;
  int v = (i < n) ? cnt[i] : 0;
  sh[tid] = v;
  __syncthreads();
  #pragma unroll
  for (int off = 1; off < 256; off <<= 1) {
    int t = (tid >= off) ? sh[tid - off] : 0;
    __syncthreads();
    sh[tid] += t;
    __syncthreads();
  }
  if (i < n) rowptr[i] = sh[tid] - v;          // exclusive, local to block
  if (tid == 255) bsum[blockIdx.x] = sh[255];  // block total
}

// 2) single-block exclusive scan of bsum[0..nb) in place (nb ~ 391)
__global__ __launch_bounds__(256) void k_scan2(int* __restrict__ bsum, int nb) {
  __shared__ int sh[256];
  __shared__ int carry;
  int tid = threadIdx.x;
  if (tid == 0) carry = 0;
  __syncthreads();
  for (int base = 0; base < nb; base += 256) {
    int i = base + tid;
    int v = (i < nb) ? bsum[i] : 0;
    sh[tid] = v;
    __syncthreads();
    #pragma unroll
    for (int off = 1; off < 256; off <<= 1) {
      int t = (tid >= off) ? sh[tid - off] : 0;
      __syncthreads();
      sh[tid] += t;
      __syncthreads();
    }
    int incl = sh[tid];
    if (i < nb) bsum[i] = carry + incl - v;    // exclusive with carry
    __syncthreads();
    if (tid == 255) carry += incl;
    __syncthreads();
  }
}

// 3) rowptr[i] += bsum[block]; cursor = rowptr; rowptr[n] = e
__global__ void k_scan3(int* __restrict__ rowptr, const int* __restrict__ bsum,
                        int* __restrict__ cursor, int n, int e) {
  int i = blockIdx.x * blockDim.x + threadIdx.x;
  if (i < n) {
    int r = rowptr[i] + bsum[i >> 8];
    rowptr[i] = r;
    cursor[i] = r;
  }
  if (i == 0) rowptr[n] = e;
}

// csr[pos] = {src, dinv[src]*dinv[dst]} bucketed by dst
__global__ void k_scatter(const int* __restrict__ src, const int* __restrict__ dst,
                          const float* __restrict__ dinv, int* __restrict__ cursor,
                          int2* __restrict__ csr, int e) {
  int i = blockIdx.x * blockDim.x + threadIdx.x;
  if (i >= e) return;
  int s = src[i], d = dst[i];
  int pos = atomicAdd(&cursor[d], 1);
  float w = dinv[s] * dinv[d];
  csr[pos] = make_int2(s, __float_as_int(w));
}

// W = W1[128,256] @ W2[256,128]; c2 = b1 @ W2
__global__ void k_w1w2(const float* __restrict__ W1, const float* __restrict__ W2,
                       const float* __restrict__ b1, float* __restrict__ W,
                       float* __restrict__ c2) {
  int r = blockIdx.x, c = threadIdx.x;   // 128 x 128
  float acc = 0.f;
  for (int k = 0; k < 256; ++k) acc = fmaf(W1[r * 256 + k], W2[k * D + c], acc);
  W[r * D + c] = acc;
  if (r == 0) {
    float a2 = 0.f;
    for (int k = 0; k < 256; ++k) a2 = fmaf(b1[k], W2[k * D + c], a2);
    c2[c] = a2;
  }
}

// ---------------- CSR aggregation: y[i] = dinv[i]^2*x[i] + sum_j w_j*x[src_j] (+bias) ----------------
template<bool BIAS>
__global__ __launch_bounds__(256) void k_agg(const float4* __restrict__ x,
                                             const int* __restrict__ rowptr,
                                             const int2* __restrict__ csr,
                                             const float* __restrict__ dinv,
                                             const float* __restrict__ bias,
                                             float4* __restrict__ y, int n) {
  int t = blockIdx.x * blockDim.x + threadIdx.x;
  int node = t >> 5, lane = t & 31;      // 32 float4 lanes per node row
  if (node >= n) return;
  float di = dinv[node];
  float s = di * di;
  float4 v = x[(size_t)node * 32 + lane];
  float4 acc;
  acc.x = v.x * s; acc.y = v.y * s; acc.z = v.z * s; acc.w = v.w * s;
  if (BIAS) {
    float4 b = ((const float4*)bias)[lane];
    acc.x += b.x; acc.y += b.y; acc.z += b.z; acc.w += b.w;
  }
  int j = rowptr[node], end = rowptr[node + 1];
  for (; j + 4 <= end; j += 4) {
    int2 e0 = csr[j], e1 = csr[j + 1], e2 = csr[j + 2], e3 = csr[j + 3];
    float4 v0 = x[(size_t)e0.x * 32 + lane];
    float4 v1 = x[(size_t)e1.x * 32 + lane];
    float4 v2 = x[(size_t)e2.x * 32 + lane];
    float4 v3 = x[(size_t)e3.x * 32 + lane];
    float w0 = __int_as_float(e0.y), w1 = __int_as_float(e1.y);
    float w2 = __int_as_float(e2.y), w3 = __int_as_float(e3.y);
    acc.x = fmaf(v0.x, w0, acc.x); acc.y = fmaf(v0.y, w0, acc.y);
    acc.z = fmaf(v0.z, w0, acc.z); acc.w = fmaf(v0.w, w0, acc.w);
    acc.x = fmaf(v1.x, w1, acc.x); acc.y = fmaf(v1.y, w1, acc.y);
    acc.z = fmaf(v1.z, w1, acc.z); acc.w = fmaf(v1.w, w1, acc.w);
    acc.x = fmaf(v2.x, w2, acc.x); acc.y = fmaf(v2.y, w2, acc.y);
    acc.z = fmaf(v2.z, w2, acc.z); acc.w = fmaf(v2.w, w2, acc.w);
    acc.x = fmaf(v3.x, w3, acc.x); acc.y = fmaf(v3.y, w3, acc.y);
    acc.z = fmaf(v3.z, w3, acc.z); acc.w = fmaf(v3.w, w3, acc.w);
  }
  for (; j < end; ++j) {
    int2 e0 = csr[j];
    float w0 = __int_as_float(e0.y);
    float4 v0 = x[(size_t)e0.x * 32 + lane];
    acc.x = fmaf(v0.x, w0, acc.x); acc.y = fmaf(v0.y, w0, acc.y);
    acc.z = fmaf(v0.z, w0, acc.z); acc.w = fmaf(v0.w, w0, acc.w);
  }
  y[(size_t)node * 32 + lane] = acc;
}

// ---------------- fp32 GEMM: Y[n,NC] = X[n,K] @ W[K,NC] (+bias) ----------------
template<int K, int NC, bool BIAS>
__global__ __launch_bounds__(256) void k_gemm(const float* __restrict__ X,
                                              const float* __restrict__ W,
                                              const float* __restrict__ bias,
                                              float* __restrict__ Y, int n) {
  __shared__ float xs[64][133];
  const int tx = threadIdx.x & 15;
  const int ty = threadIdx.x >> 4;
  const int ty4 = ty * 4;
  const int row0 = blockIdx.x * 64;
  const int col0 = blockIdx.y * 64 + tx * 4;

  float acc[4][4] = {};

  for (int k0 = 0; k0 < K; k0 += 128) {
    __syncthreads();
    #pragma unroll
    for (int i = 0; i < 8; ++i) {
      int flat4 = threadIdx.x + i * 256;
      int r = flat4 >> 5;
      int kk = (flat4 & 31) * 4;
      float4 v = make_float4(0.f, 0.f, 0.f, 0.f);
      if (row0 + r < n) v = *(const float4*)(X + (size_t)(row0 + r) * K + k0 + kk);
      xs[r][kk + 0] = v.x; xs[r][kk + 1] = v.y; xs[r][kk + 2] = v.z; xs[r][kk + 3] = v.w;
    }
    __syncthreads();

    #pragma unroll 8
    for (int k = 0; k < 128; ++k) {
      float4 w4 = *(const float4*)(W + (size_t)(k0 + k) * NC + col0);
      float xa = xs[ty4 + 0][k];
      float xb = xs[ty4 + 1][k];
      float xc = xs[ty4 + 2][k];
      float xd = xs[ty4 + 3][k];
      acc[0][0] = fmaf(xa, w4.x, acc[0][0]); acc[0][1] = fmaf(xa, w4.y, acc[0][1]);
      acc[0][2] = fmaf(xa, w4.z, acc[0][2]); acc[0][3] = fmaf(xa, w4.w, acc[0][3]);
      acc[1][0] = fmaf(xb, w4.x, acc[1][0]); acc[1][1] = fmaf(xb, w4.y, acc[1][1]);
      acc[1][2] = fmaf(xb, w4.z, acc[1][2]); acc[1][3] = fmaf(xb, w4.w, acc[1][3]);
      acc[2][0] = fmaf(xc, w4.x, acc[2][0]); acc[2][1] = fmaf(xc, w4.y, acc[2][1]);
      acc[2][2] = fmaf(xc, w4.z, acc[2][2]); acc[2][3] = fmaf(xc, w4.w, acc[2][3]);
      acc[3][0] = fmaf(xd, w4.x, acc[3][0]); acc[3][1] = fmaf(xd, w4.y, acc[3][1]);
      acc[3][2] = fmaf(xd, w4.z, acc[3][2]); acc[3][3] = fmaf(xd, w4.w, acc[3][3]);
    }
  }

  float4 b4 = make_float4(0.f, 0.f, 0.f, 0.f);
  if (BIAS) b4 = *(const float4*)(bias + col0);
  #pragma unroll
  for (int r = 0; r < 4; ++r) {
    int row = row0 + ty4 + r;
    if (row < n) {
      float4 o;
      o.x = acc[r][0] + b4.x; o.y = acc[r][1] + b4.y;
      o.z = acc[r][2] + b4.z; o.w = acc[r][3] + b4.w;
      *(float4*)(Y + (size_t)row * NC + col0) = o;
    }
  }
}

extern "C" void kernel_launch(void* const* d_in, const int* in_sizes, int n_in,
                              void* d_out, int out_size, void* d_ws, size_t ws_size,
                              hipStream_t stream) {
  const float* emb = (const float*)d_in[0];   // [n,128]
  const float* W1  = (const float*)d_in[1];   // [128,256]
  const float* b1  = (const float*)d_in[2];   // [256]
  const float* W2  = (const float*)d_in[3];   // [256,128]
  const float* b2  = (const float*)d_in[4];   // [128]
  const int*   ei  = (const int*)d_in[5];     // [2,E] (int32 by harness)

  const int n = in_sizes[0] / D;
  const int e = in_sizes[5] / 2;
  const int* src = ei;
  const int* dst = ei + e;

  const int B = 256;
  const int gn = (n + B - 1) / B;   // also = number of scan blocks
  const int ge = (e + B - 1) / B;

  // workspace carve-up (all 256B-aligned)
  char* ws = (char*)d_ws;
  size_t off = 0;
  auto alloc = [&](size_t bytes) { void* p = ws + off; off = (off + bytes + 255) & ~(size_t)255; return p; };
  int*   cnt    = (int*)  alloc((size_t)n * 4);
  float* dinv   = (float*)alloc((size_t)n * 4);
  int*   rowptr = (int*)  alloc((size_t)(n + 1) * 4);
  int*   cursor = (int*)  alloc((size_t)n * 4);
  int*   bsum   = (int*)  alloc((size_t)gn * 4);
  int2*  csr    = (int2*) alloc((size_t)e * 8);
  float* Wc     = (float*)alloc((size_t)D * D * 4);
  float* c2     = (float*)alloc((size_t)D * 4);
  float* S1     = (float*)alloc((size_t)n * D * 4);
  float* Z      = (float*)alloc((size_t)n * D * 4);
  float* out    = (float*)d_out;

  // CSR build + norms
  k_zero_i<<<gn, B, 0, stream>>>(cnt, n);
  k_count<<<ge, B, 0, stream>>>(dst, cnt, e);
  k_dinv<<<gn, B, 0, stream>>>(cnt, dinv, n);
  k_scan1<<<gn, B, 0, stream>>>(cnt, rowptr, bsum, n);
  k_scan2<<<1, B, 0, stream>>>(bsum, gn);
  k_scan3<<<gn, B, 0, stream>>>(rowptr, bsum, cursor, n, e);
  k_scatter<<<ge, B, 0, stream>>>(src, dst, dinv, cursor, csr, e);

  // fold W = W1@W2, c2 = b1@W2
  k_w1w2<<<D, D, 0, stream>>>(W1, W2, b1, Wc, c2);

  // S1 = A * emb
  {
    long long t = (long long)n * 32;
    k_agg<false><<<(int)((t + B - 1) / B), B, 0, stream>>>(
        (const float4*)emb, rowptr, csr, dinv, nullptr, (float4*)S1, n);
  }
  // Z = S1 @ W + c2
  {
    dim3 grid((n + 63) / 64, D / 64);
    k_gemm<128, 128, true><<<grid, 256, 0, stream>>>(S1, Wc, c2, Z, n);
  }
  // out = A * Z + b2
  {
    long long t = (long long)n * 32;
    k_agg<true><<<(int)((t + B - 1) / B), B, 0, stream>>>(
        (const float4*)Z, rowptr, csr, dinv, b2, (float4*)out, n);
  }
}